// Round 9
// baseline (259.070 us; speedup 1.0000x reference)
//
#include <hip/hip_runtime.h>
#include <math.h>

#define B_    2
#define L_    2048
#define D_    1024
#define H_    16
#define HD_   64
#define HALF_ 128
#define TQ    32          // queries per attention block
#define PST   296         // bf16 P-slab row stride (shorts); 16B-aligned, bank-tiled

typedef __attribute__((ext_vector_type(8))) short short8;
typedef __attribute__((ext_vector_type(4))) float f32x4;

// ---- bf16 helpers (bitwise, RNE) -----------------------------------------
__device__ __forceinline__ unsigned short f2bf(float x) {
  unsigned int u = __float_as_uint(x);
  u = (u + 0x7fffu + ((u >> 16) & 1u)) >> 16;
  return (unsigned short)u;
}
__device__ __forceinline__ float bf2f(unsigned short b) {
  return __uint_as_float(((unsigned int)b) << 16);
}
__device__ __forceinline__ void split1(float a, unsigned short& h, unsigned short& l) {
  h = f2bf(a);
  l = f2bf(a - bf2f(h));
}

__device__ __forceinline__ void async_cp16(const unsigned short* g, unsigned short* l) {
  __builtin_amdgcn_global_load_lds(
      (const __attribute__((address_space(1))) unsigned int*)g,
      (__attribute__((address_space(3))) unsigned int*)l, 16, 0, 0);
}

// ---------------------------------------------------------------------------
// prep: fused (a) x -> hi/lo bf16 split, (b) w_qkv transpose+round,
//       (c) w_out transpose+round.  Branch is block-uniform.
// ---------------------------------------------------------------------------
__device__ __forceinline__ void tr_round32(const float* __restrict__ in,
                                           unsigned short* __restrict__ hi,
                                           int N, int K, int n0, int k0,
                                           float (*t)[33], int tid) {
  {
    const int kl = tid >> 3, nl = (tid & 7) * 4;
    const float4 v = *(const float4*)&in[(size_t)(k0 + kl) * N + n0 + nl];
    t[kl][nl + 0] = v.x; t[kl][nl + 1] = v.y;
    t[kl][nl + 2] = v.z; t[kl][nl + 3] = v.w;
  }
  __syncthreads();
  {
    const int no = tid >> 3, ko = (tid & 7) * 4;
    ushort4 h;
    h.x = f2bf(t[ko + 0][no]);
    h.y = f2bf(t[ko + 1][no]);
    h.z = f2bf(t[ko + 2][no]);
    h.w = f2bf(t[ko + 3][no]);
    *(ushort4*)&hi[(size_t)(n0 + no) * K + k0 + ko] = h;
  }
}

__global__ __launch_bounds__(256) void prep(const float* __restrict__ x,
                                            unsigned short* __restrict__ x_hi,
                                            unsigned short* __restrict__ x_lo,
                                            const float* __restrict__ w_qkv,
                                            unsigned short* __restrict__ wqkvT,
                                            const float* __restrict__ w_out,
                                            unsigned short* __restrict__ woutT) {
  __shared__ float t[32][33];
  const int bx = blockIdx.x, tid = threadIdx.x;
  if (bx < 4096) {
    const int i = (bx * 256 + tid) * 4;
    const float4 a = *(const float4*)&x[i];
    ushort4 h, l;
    split1(a.x, h.x, l.x);
    split1(a.y, h.y, l.y);
    split1(a.z, h.z, l.z);
    split1(a.w, h.w, l.w);
    *(ushort4*)&x_hi[i] = h;
    *(ushort4*)&x_lo[i] = l;
  } else if (bx < 7168) {
    const int tb = bx - 4096;  // 96 x 32 tiles
    tr_round32(w_qkv, wqkvT, 3 * D_, D_, (tb % 96) * 32, (tb / 96) * 32, t, tid);
  } else {
    const int tb = bx - 7168;  // 32 x 32 tiles
    tr_round32(w_out, woutT, D_, D_, (tb % 32) * 32, (tb / 32) * 32, t, tid);
  }
}

// ---------------------------------------------------------------------------
// QKV GEMM. 128x128 tile, BK=32, 4 waves.
// Q,K column-tiles (n0 < 2048): SINGLE product ah@bh — their outputs are
//   consumed as bf16-hi only by attention, so the al term is below the
//   storage quantum. Epilogue: scalar bf16 stores to qk [B,L,2,1024].
// V column-tiles (n0 >= 2048): 2-product (attention consumes vh+vl).
//   Epilogue: vT_h/vT_l [B,1024,L] transposed planes, ushort4 stores.
// ---------------------------------------------------------------------------
__global__ __launch_bounds__(256) void gemm_qkv(const unsigned short* __restrict__ Ah,
                                                const unsigned short* __restrict__ Al,
                                                const unsigned short* __restrict__ Bh,
                                                const float* __restrict__ bias,
                                                unsigned short* __restrict__ qk_h,
                                                unsigned short* __restrict__ vT_h,
                                                unsigned short* __restrict__ vT_l,
                                                int N, int K) {
  __shared__ unsigned short sm[3 * 4096];  // 24 KB: Ah | Al | Bh
  const int tid  = threadIdx.x;
  const int wave = tid >> 6, lane = tid & 63;
  const int m0 = blockIdx.y * 128, n0 = blockIdx.x * 128;
  const int wm = (wave >> 1) * 64, wn = (wave & 1) * 64;
  const int quad = lane >> 4, ln16 = lane & 15;
  const bool twoProd = (n0 >= 2048);  // V tiles only

  const unsigned short* src = (wave == 0) ? Ah : (wave == 1) ? Al : Bh;
  const int baserow = (wave < 2) ? m0 : n0;
  size_t goff[8];
#pragma unroll
  for (int inst = 0; inst < 8; ++inst) {
    const int r = inst * 16 + (lane >> 2);
    const int q = (lane & 3) ^ ((r >> 1) & 3);
    goff[inst] = (size_t)(baserow + r) * K + q * 8;
  }
  unsigned short* dst0 = &sm[(wave < 3 ? wave : 2) * 4096];
  const bool doStage = (wave == 0) || (wave == 2) || (wave == 1 && twoProd);

  int offA[4], offB[4];
#pragma unroll
  for (int t = 0; t < 4; ++t) {
    const int r = wm + t * 16 + ln16;
    offA[t] = r * 64 + ((quad ^ ((r >> 1) & 3)) * 16);
    const int rn = wn + t * 16 + ln16;
    offB[t] = rn * 64 + ((quad ^ ((rn >> 1) & 3)) * 16);
  }

  f32x4 acc[4][4] = {};
  const char* smb = (const char*)sm;

  for (int k0 = 0; k0 < K; k0 += 32) {
    if (doStage) {
#pragma unroll
      for (int inst = 0; inst < 8; ++inst)
        async_cp16(src + goff[inst] + k0,
                   (unsigned short*)((char*)dst0 + inst * 1024));
    }
    __syncthreads();

    short8 ah[4], al[4], bh[4];
#pragma unroll
    for (int t = 0; t < 4; ++t) {
      ah[t] = *(const short8*)(smb + offA[t]);
      bh[t] = *(const short8*)(smb + 16384 + offB[t]);
    }
#pragma unroll
    for (int t = 0; t < 4; ++t)
#pragma unroll
      for (int u = 0; u < 4; ++u)
        acc[t][u] = __builtin_amdgcn_mfma_f32_16x16x32_bf16(ah[t], bh[u], acc[t][u], 0, 0, 0);
    if (twoProd) {
#pragma unroll
      for (int t = 0; t < 4; ++t) al[t] = *(const short8*)(smb + 8192 + offA[t]);
#pragma unroll
      for (int t = 0; t < 4; ++t)
#pragma unroll
        for (int u = 0; u < 4; ++u)
          acc[t][u] = __builtin_amdgcn_mfma_f32_16x16x32_bf16(al[t], bh[u], acc[t][u], 0, 0, 0);
    }
    __syncthreads();
  }

#pragma unroll
  for (int u = 0; u < 4; ++u) {
    const int col = n0 + wn + u * 16 + ln16;
    const float bv = bias[col];
    const int slot = col >> 10;   // 0=q,1=k,2=v (wave-uniform per tile)
    const int hd   = col & 1023;
#pragma unroll
    for (int t = 0; t < 4; ++t) {
      const int row0 = m0 + wm + t * 16 + quad * 4;
      if (slot < 2) {
#pragma unroll
        for (int e = 0; e < 4; ++e) {
          const size_t o = ((size_t)(row0 + e) * 2 + slot) * 1024 + hd;
          qk_h[o] = f2bf(acc[t][u][e] + bv);
        }
      } else {
        const int bb = row0 >> 11, l0 = row0 & 2047;
        ushort4 vh, vl;
        split1(acc[t][u][0] + bv, vh.x, vl.x);
        split1(acc[t][u][1] + bv, vh.y, vl.y);
        split1(acc[t][u][2] + bv, vh.z, vl.z);
        split1(acc[t][u][3] + bv, vh.w, vl.w);
        const size_t o = ((size_t)bb * 1024 + hd) * 2048 + l0;
        *(ushort4*)&vT_h[o] = vh;
        *(ushort4*)&vT_l[o] = vl;
      }
    }
  }
}

// ---------------------------------------------------------------------------
// Out-projection GEMM: C = (Ah+Al) @ Bh^T + bias, fp32 out.
// 128x64 tile, BK=32, 512 blocks (2/CU). 20 KB LDS.
// ---------------------------------------------------------------------------
__global__ __launch_bounds__(256) void gemm_n64(const unsigned short* __restrict__ Ah,
                                                const unsigned short* __restrict__ Al,
                                                const unsigned short* __restrict__ Bh,
                                                const float* __restrict__ bias,
                                                float* __restrict__ C,
                                                int N, int K) {
  __shared__ unsigned short sm[2 * 4096 + 2048];  // 20 KB: Ah | Al | Bh
  const int tid  = threadIdx.x;
  const int wave = tid >> 6, lane = tid & 63;
  const int m0 = blockIdx.y * 128, n0 = blockIdx.x * 64;
  const int quad = lane >> 4, ln16 = lane & 15;
  const int wm = wave * 32;

  const unsigned short* src = (wave == 0) ? Ah : (wave == 1) ? Al : Bh;
  const int baserow = (wave < 2) ? m0 : n0;
  size_t goff[8];
#pragma unroll
  for (int inst = 0; inst < 8; ++inst) {
    const int r = inst * 16 + (lane >> 2);
    const int q = (lane & 3) ^ ((r >> 1) & 3);
    goff[inst] = (size_t)(baserow + r) * K + q * 8;
  }
  unsigned short* dst0 = &sm[(wave < 2 ? wave : 2) * 4096];

  int offA[2], offB[4];
#pragma unroll
  for (int t = 0; t < 2; ++t) {
    const int r = wm + t * 16 + ln16;
    offA[t] = r * 64 + ((quad ^ ((r >> 1) & 3)) * 16);
  }
#pragma unroll
  for (int u = 0; u < 4; ++u) {
    const int rn = u * 16 + ln16;
    offB[u] = rn * 64 + ((quad ^ ((rn >> 1) & 3)) * 16);
  }

  f32x4 acc[2][4] = {};
  const char* smb = (const char*)sm;

  for (int k0 = 0; k0 < K; k0 += 32) {
    if (wave < 2) {
#pragma unroll
      for (int inst = 0; inst < 8; ++inst)
        async_cp16(src + goff[inst] + k0,
                   (unsigned short*)((char*)dst0 + inst * 1024));
    } else if (wave == 2) {
#pragma unroll
      for (int inst = 0; inst < 4; ++inst)
        async_cp16(src + goff[inst] + k0,
                   (unsigned short*)((char*)dst0 + inst * 1024));
    }
    __syncthreads();

    short8 ah[2], al[2], bh[4];
#pragma unroll
    for (int t = 0; t < 2; ++t) {
      ah[t] = *(const short8*)(smb + offA[t]);
      al[t] = *(const short8*)(smb + 8192 + offA[t]);
    }
#pragma unroll
    for (int u = 0; u < 4; ++u) bh[u] = *(const short8*)(smb + 16384 + offB[u]);
#pragma unroll
    for (int t = 0; t < 2; ++t)
#pragma unroll
      for (int u = 0; u < 4; ++u) {
        acc[t][u] = __builtin_amdgcn_mfma_f32_16x16x32_bf16(ah[t], bh[u], acc[t][u], 0, 0, 0);
        acc[t][u] = __builtin_amdgcn_mfma_f32_16x16x32_bf16(al[t], bh[u], acc[t][u], 0, 0, 0);
      }
    __syncthreads();
  }

#pragma unroll
  for (int u = 0; u < 4; ++u) {
    const int col = n0 + u * 16 + ln16;
    const float bv = bias[col];
#pragma unroll
    for (int t = 0; t < 2; ++t) {
      const int row0 = m0 + wm + t * 16 + quad * 4;
#pragma unroll
      for (int e = 0; e < 4; ++e)
        C[(size_t)(row0 + e) * N + col] = acc[t][u][e] + bv;
    }
  }
}

// ---------------------------------------------------------------------------
// MFMA sliding-window attention, register softmax. Block = (b,h,32 queries).
// Phase 1: S = Qh @ Kh^T (pure bf16 — score-path error budget allows it),
//          unrolled; exp in-reg (no rowmax, scores bounded ~1.3),
//          unnormalized P -> bf16 LDS, row sums via shfl_xor + one LDS
//          exchange. ONE barrier.
// Phase 2: O = P @ (Vh+Vl), V frags from separate hi/lo planes (16B loads).
// Epilogue: scale by 1/rowsum, LDS bounce, coalesced split-bf16 stores.
// ---------------------------------------------------------------------------
__global__ __launch_bounds__(256, 4) void attn_mfma(
    const unsigned short* __restrict__ qk_h,
    const unsigned short* __restrict__ vT_h,
    const unsigned short* __restrict__ vT_l,
    unsigned short* __restrict__ attn_h,
    unsigned short* __restrict__ attn_l) {
  __shared__ unsigned short P[TQ * PST];  // 18944 B (epilogue reuses as fp32)
  __shared__ float redS[2][32];

  const int b   = blockIdx.z;
  const int h   = blockIdx.y;
  const int i0  = blockIdx.x * TQ;
  const int tid = threadIdx.x;
  const int wave = tid >> 6, lane = tid & 63;
  const int quad = lane >> 4, ln16 = lane & 15;
  const int mt = wave >> 1, np = wave & 1;
  const int jlo = i0 - HALF_;
  const int rbase = mt * 16 + quad * 4;

  // ---- phase 1: scores -> exp -> P(bf16, unnormalized) + row sums --------
  float s[4] = {0.f, 0.f, 0.f, 0.f};
  {
    const size_t qbase =
        ((size_t)(b * L_ + i0 + mt * 16 + ln16) * 2 + 0) * 1024 + h * 64 + quad * 8;
    const short8 qh0 = *(const short8*)&qk_h[qbase];
    const short8 qh1 = *(const short8*)&qk_h[qbase + 32];

#pragma unroll
    for (int c = 0; c < 9; ++c) {
      const int nt   = np + 2 * c;
      const int jabs = jlo + nt * 16 + ln16;
      const int jcl  = min(max(jabs, 0), L_ - 1);
      const size_t kbase =
          ((size_t)(b * L_ + jcl) * 2 + 1) * 1024 + h * 64 + quad * 8;
      const short8 kh0 = *(const short8*)&qk_h[kbase];
      const short8 kh1 = *(const short8*)&qk_h[kbase + 32];

      f32x4 a = {};
      a = __builtin_amdgcn_mfma_f32_16x16x32_bf16(qh0, kh0, a, 0, 0, 0);
      a = __builtin_amdgcn_mfma_f32_16x16x32_bf16(qh1, kh1, a, 0, 0, 0);

      const int colj = nt * 16 + ln16;
#pragma unroll
      for (int e = 0; e < 4; ++e) {
        const int iabs = i0 + rbase + e;
        const bool ok = (jabs >= 0) && (jabs < L_) && (abs(iabs - jabs) <= HALF_);
        const float ev = ok ? __expf(a[e] * 0.125f) : 0.f;
        s[e] += ev;
        P[(rbase + e) * PST + colj] = f2bf(ev);
      }
    }
  }
  // row-sum reduce across the 16 ln16 lanes (stays within quad)
#pragma unroll
  for (int e = 0; e < 4; ++e) {
    s[e] += __shfl_xor(s[e], 1);
    s[e] += __shfl_xor(s[e], 2);
    s[e] += __shfl_xor(s[e], 4);
    s[e] += __shfl_xor(s[e], 8);
  }
  if (ln16 == 0) {
#pragma unroll
    for (int e = 0; e < 4; ++e) redS[np][rbase + e] = s[e];
  }
  __syncthreads();  // covers P writes AND redS exchange
  float rinv[4];
#pragma unroll
  for (int e = 0; e < 4; ++e) rinv[e] = 1.f / (s[e] + redS[np ^ 1][rbase + e]);

  // ---- phase 2: O = P @ V (separate hi/lo planes) ------------------------
  f32x4 o[2] = {};
  {
    const int dp = np;
    const char* pb = (const char*)P;
#pragma unroll
    for (int c = 0; c < 9; ++c) {
      const short8 pf =
          *(const short8*)(pb + (mt * 16 + ln16) * (PST * 2) + c * 64 + quad * 16);
      int j0 = jlo + c * 32 + quad * 8;
      j0 = min(max(j0, 0), L_ - 8);
#pragma unroll
      for (int t = 0; t < 2; ++t) {
        const size_t vb =
            ((size_t)b * 1024 + h * 64 + dp * 32 + t * 16 + ln16) * 2048 + j0;
        const short8 vh = *(const short8*)&vT_h[vb];
        const short8 vl = *(const short8*)&vT_l[vb];
        o[t] = __builtin_amdgcn_mfma_f32_16x16x32_bf16(pf, vh, o[t], 0, 0, 0);
        o[t] = __builtin_amdgcn_mfma_f32_16x16x32_bf16(pf, vl, o[t], 0, 0, 0);
      }
    }
  }

  // ---- epilogue: normalize, LDS bounce, coalesced split-bf16 stores ------
  __syncthreads();  // P slab dead
  float* ob = (float*)P;  // 32 rows x 68-float stride = 8704 B
  {
    const int dp = np;
#pragma unroll
    for (int t = 0; t < 2; ++t)
#pragma unroll
      for (int e = 0; e < 4; ++e)
        ob[(rbase + e) * 68 + dp * 32 + t * 16 + ln16] = o[t][e] * rinv[e];
  }
  __syncthreads();
  {
    const int rr = tid >> 3, ck = tid & 7;
    const float* rp = ob + rr * 68 + ck * 8;
    const float4 f0 = *(const float4*)&rp[0];
    const float4 f1 = *(const float4*)&rp[4];
    float fv[8] = {f0.x, f0.y, f0.z, f0.w, f1.x, f1.y, f1.z, f1.w};
    short8 hh, ll;
#pragma unroll
    for (int i = 0; i < 8; ++i) {
      unsigned short h2, l2;
      split1(fv[i], h2, l2);
      hh[i] = (short)h2; ll[i] = (short)l2;
    }
    const size_t oo = ((size_t)(b * L_ + i0 + rr)) * 1024 + h * 64 + ck * 8;
    *(short8*)&attn_h[oo] = hh;
    *(short8*)&attn_l[oo] = ll;
  }
}

// ---------------------------------------------------------------------------
extern "C" void kernel_launch(void* const* d_in, const int* in_sizes, int n_in,
                              void* d_out, int out_size, void* d_ws, size_t ws_size,
                              hipStream_t stream) {
  const float* x     = (const float*)d_in[0];
  const float* w_qkv = (const float*)d_in[1];
  const float* b_qkv = (const float*)d_in[2];
  const float* w_out = (const float*)d_in[3];
  const float* b_out = (const float*)d_in[4];
  float* out = (float*)d_out;

  const int M = B_ * L_;  // 4096

  // workspace layout (bytes), total 76 MiB:
  //   x_hi @0 (8MiB)     x_lo @8MiB (8MiB)     [dead after QKV gemm]
  //   wqkvT @16MiB (6MiB)
  //   woutT @22MiB (2MiB)
  //   qk_hi @28MiB (16MiB)                     [B,L,2,1024] hi-only
  //   vT_h @60MiB (8MiB)    vT_l @68MiB (8MiB) [B,1024,L]
  // aliases over dead x region: attn_hi @0, attn_lo @8MiB
  char* ws = (char*)d_ws;
  unsigned short* x_hi    = (unsigned short*)(ws + 0);
  unsigned short* x_lo    = (unsigned short*)(ws + 8388608);
  unsigned short* wqkvT   = (unsigned short*)(ws + 16777216);
  unsigned short* woutT   = (unsigned short*)(ws + 23068672);
  unsigned short* qk_hi   = (unsigned short*)(ws + 29360128);
  unsigned short* vT_h    = (unsigned short*)(ws + 62914560);
  unsigned short* vT_l    = (unsigned short*)(ws + 71303168);
  unsigned short* attn_hi = (unsigned short*)(ws + 0);
  unsigned short* attn_lo = (unsigned short*)(ws + 8388608);

  // 1) fused prep: x split + both weight transposes
  prep<<<8192, 256, 0, stream>>>(x, x_hi, x_lo, w_qkv, wqkvT, w_out, woutT);
  // 2) QKV projection -> qk (bf16 hi) + vT (split planes)
  {
    dim3 g(3 * D_ / 128, M / 128);
    gemm_qkv<<<g, 256, 0, stream>>>(x_hi, x_lo, wqkvT, b_qkv,
                                    qk_hi, vT_h, vT_l, 3 * D_, D_);
  }
  // 3) MFMA banded attention -> attn split bf16 (aliases dead x)
  {
    dim3 g(L_ / TQ, H_, B_);
    attn_mfma<<<g, 256, 0, stream>>>(qk_hi, vT_h, vT_l, attn_hi, attn_lo);
  }
  // 4) output projection -> fp32 d_out (128x64 tiles, 512 blocks = 2/CU)
  {
    dim3 g(D_ / 64, M / 128);
    gemm_n64<<<g, 256, 0, stream>>>(attn_hi, attn_lo, woutT, b_out, out,
                                    D_, D_);
  }
}

// Round 10
// 219.135 us; speedup vs baseline: 1.1822x; 1.1822x over previous
//
#include <hip/hip_runtime.h>
#include <math.h>

#define B_    2
#define L_    2048
#define D_    1024
#define H_    16
#define HD_   64
#define HALF_ 128
#define TQ    32          // queries per attention block
#define PST   296         // bf16 P-slab row stride (shorts); 16B-aligned, bank-tiled

typedef __attribute__((ext_vector_type(8))) short short8;
typedef __attribute__((ext_vector_type(4))) float f32x4;

// ---- bf16 helpers (bitwise, RNE) -----------------------------------------
__device__ __forceinline__ unsigned short f2bf(float x) {
  unsigned int u = __float_as_uint(x);
  u = (u + 0x7fffu + ((u >> 16) & 1u)) >> 16;
  return (unsigned short)u;
}
__device__ __forceinline__ float bf2f(unsigned short b) {
  return __uint_as_float(((unsigned int)b) << 16);
}
__device__ __forceinline__ void split1(float a, unsigned short& h, unsigned short& l) {
  h = f2bf(a);
  l = f2bf(a - bf2f(h));
}

__device__ __forceinline__ void async_cp16(const unsigned short* g, unsigned short* l) {
  __builtin_amdgcn_global_load_lds(
      (const __attribute__((address_space(1))) unsigned int*)g,
      (__attribute__((address_space(3))) unsigned int*)l, 16, 0, 0);
}

// ---------------------------------------------------------------------------
// prep: fused (a) x -> hi/lo bf16 split, (b) w_qkv transpose+round,
//       (c) w_out transpose+round.  Branch is block-uniform.
// ---------------------------------------------------------------------------
__device__ __forceinline__ void tr_round32(const float* __restrict__ in,
                                           unsigned short* __restrict__ hi,
                                           int N, int K, int n0, int k0,
                                           float (*t)[33], int tid) {
  {
    const int kl = tid >> 3, nl = (tid & 7) * 4;
    const float4 v = *(const float4*)&in[(size_t)(k0 + kl) * N + n0 + nl];
    t[kl][nl + 0] = v.x; t[kl][nl + 1] = v.y;
    t[kl][nl + 2] = v.z; t[kl][nl + 3] = v.w;
  }
  __syncthreads();
  {
    const int no = tid >> 3, ko = (tid & 7) * 4;
    ushort4 h;
    h.x = f2bf(t[ko + 0][no]);
    h.y = f2bf(t[ko + 1][no]);
    h.z = f2bf(t[ko + 2][no]);
    h.w = f2bf(t[ko + 3][no]);
    *(ushort4*)&hi[(size_t)(n0 + no) * K + k0 + ko] = h;
  }
}

__global__ __launch_bounds__(256) void prep(const float* __restrict__ x,
                                            unsigned short* __restrict__ x_hi,
                                            unsigned short* __restrict__ x_lo,
                                            const float* __restrict__ w_qkv,
                                            unsigned short* __restrict__ wqkvT,
                                            const float* __restrict__ w_out,
                                            unsigned short* __restrict__ woutT) {
  __shared__ float t[32][33];
  const int bx = blockIdx.x, tid = threadIdx.x;
  if (bx < 4096) {
    const int i = (bx * 256 + tid) * 4;
    const float4 a = *(const float4*)&x[i];
    ushort4 h, l;
    split1(a.x, h.x, l.x);
    split1(a.y, h.y, l.y);
    split1(a.z, h.z, l.z);
    split1(a.w, h.w, l.w);
    *(ushort4*)&x_hi[i] = h;
    *(ushort4*)&x_lo[i] = l;
  } else if (bx < 7168) {
    const int tb = bx - 4096;  // 96 x 32 tiles
    tr_round32(w_qkv, wqkvT, 3 * D_, D_, (tb % 96) * 32, (tb / 96) * 32, t, tid);
  } else {
    const int tb = bx - 7168;  // 32 x 32 tiles
    tr_round32(w_out, woutT, D_, D_, (tb % 32) * 32, (tb / 32) * 32, t, tid);
  }
}

// ---------------------------------------------------------------------------
// 2-product split-bf16 MFMA GEMM (QKV): C = (Ah+Al) @ Bh^T + bias.
// 128x128 tile, BK=32, 4 waves (3 stage, all compute). r8-exact K-loop and
// epilogue: NO conditionals in the K-loop (r6/r7/r9 all regressed from them).
// Epilogue: q,k -> qk_h/qk_l [B,L,2,1024] scalar stores (both planes);
//           v -> vT_h/vT_l [B,1024,L] separate planes, ushort4 stores.
// ---------------------------------------------------------------------------
__global__ __launch_bounds__(256) void gemm_qkv(const unsigned short* __restrict__ Ah,
                                                const unsigned short* __restrict__ Al,
                                                const unsigned short* __restrict__ Bh,
                                                const float* __restrict__ bias,
                                                unsigned short* __restrict__ qk_h,
                                                unsigned short* __restrict__ qk_l,
                                                unsigned short* __restrict__ vT_h,
                                                unsigned short* __restrict__ vT_l,
                                                int N, int K) {
  __shared__ unsigned short sm[3 * 4096];  // 24 KB: Ah | Al | Bh
  const int tid  = threadIdx.x;
  const int wave = tid >> 6, lane = tid & 63;
  const int m0 = blockIdx.y * 128, n0 = blockIdx.x * 128;
  const int wm = (wave >> 1) * 64, wn = (wave & 1) * 64;
  const int quad = lane >> 4, ln16 = lane & 15;

  const unsigned short* src = (wave == 0) ? Ah : (wave == 1) ? Al : Bh;
  const int baserow = (wave < 2) ? m0 : n0;
  size_t goff[8];
#pragma unroll
  for (int inst = 0; inst < 8; ++inst) {
    const int r = inst * 16 + (lane >> 2);
    const int q = (lane & 3) ^ ((r >> 1) & 3);
    goff[inst] = (size_t)(baserow + r) * K + q * 8;
  }
  unsigned short* dst0 = &sm[(wave < 3 ? wave : 2) * 4096];

  int offA[4], offB[4];
#pragma unroll
  for (int t = 0; t < 4; ++t) {
    const int r = wm + t * 16 + ln16;
    offA[t] = r * 64 + ((quad ^ ((r >> 1) & 3)) * 16);
    const int rn = wn + t * 16 + ln16;
    offB[t] = rn * 64 + ((quad ^ ((rn >> 1) & 3)) * 16);
  }

  f32x4 acc[4][4] = {};
  const char* smb = (const char*)sm;

  for (int k0 = 0; k0 < K; k0 += 32) {
    if (wave < 3) {
#pragma unroll
      for (int inst = 0; inst < 8; ++inst)
        async_cp16(src + goff[inst] + k0,
                   (unsigned short*)((char*)dst0 + inst * 1024));
    }
    __syncthreads();

    short8 ah[4], al[4], bh[4];
#pragma unroll
    for (int t = 0; t < 4; ++t) {
      ah[t] = *(const short8*)(smb + offA[t]);
      al[t] = *(const short8*)(smb + 8192 + offA[t]);
      bh[t] = *(const short8*)(smb + 16384 + offB[t]);
    }
#pragma unroll
    for (int t = 0; t < 4; ++t)
#pragma unroll
      for (int u = 0; u < 4; ++u) {
        acc[t][u] = __builtin_amdgcn_mfma_f32_16x16x32_bf16(ah[t], bh[u], acc[t][u], 0, 0, 0);
        acc[t][u] = __builtin_amdgcn_mfma_f32_16x16x32_bf16(al[t], bh[u], acc[t][u], 0, 0, 0);
      }
    __syncthreads();
  }

#pragma unroll
  for (int u = 0; u < 4; ++u) {
    const int col = n0 + wn + u * 16 + ln16;
    const float bv = bias[col];
    const int slot = col >> 10;   // 0=q,1=k,2=v (wave-uniform per tile)
    const int hd   = col & 1023;
#pragma unroll
    for (int t = 0; t < 4; ++t) {
      const int row0 = m0 + wm + t * 16 + quad * 4;
      if (slot < 2) {
#pragma unroll
        for (int e = 0; e < 4; ++e) {
          unsigned short hh, ll;
          split1(acc[t][u][e] + bv, hh, ll);
          const size_t o = ((size_t)(row0 + e) * 2 + slot) * 1024 + hd;
          qk_h[o] = hh;
          qk_l[o] = ll;
        }
      } else {
        const int bb = row0 >> 11, l0 = row0 & 2047;
        ushort4 vh, vl;
        split1(acc[t][u][0] + bv, vh.x, vl.x);
        split1(acc[t][u][1] + bv, vh.y, vl.y);
        split1(acc[t][u][2] + bv, vh.z, vl.z);
        split1(acc[t][u][3] + bv, vh.w, vl.w);
        const size_t o = ((size_t)bb * 1024 + hd) * 2048 + l0;
        *(ushort4*)&vT_h[o] = vh;
        *(ushort4*)&vT_l[o] = vl;
      }
    }
  }
}

// ---------------------------------------------------------------------------
// Out-projection GEMM: C = (Ah+Al) @ Bh^T + bias, fp32 out.
// 128x64 tile, BK=32, 512 blocks (2/CU). 20 KB LDS.
// ---------------------------------------------------------------------------
__global__ __launch_bounds__(256) void gemm_n64(const unsigned short* __restrict__ Ah,
                                                const unsigned short* __restrict__ Al,
                                                const unsigned short* __restrict__ Bh,
                                                const float* __restrict__ bias,
                                                float* __restrict__ C,
                                                int N, int K) {
  __shared__ unsigned short sm[2 * 4096 + 2048];  // 20 KB: Ah | Al | Bh
  const int tid  = threadIdx.x;
  const int wave = tid >> 6, lane = tid & 63;
  const int m0 = blockIdx.y * 128, n0 = blockIdx.x * 64;
  const int quad = lane >> 4, ln16 = lane & 15;
  const int wm = wave * 32;

  const unsigned short* src = (wave == 0) ? Ah : (wave == 1) ? Al : Bh;
  const int baserow = (wave < 2) ? m0 : n0;
  size_t goff[8];
#pragma unroll
  for (int inst = 0; inst < 8; ++inst) {
    const int r = inst * 16 + (lane >> 2);
    const int q = (lane & 3) ^ ((r >> 1) & 3);
    goff[inst] = (size_t)(baserow + r) * K + q * 8;
  }
  unsigned short* dst0 = &sm[(wave < 2 ? wave : 2) * 4096];

  int offA[2], offB[4];
#pragma unroll
  for (int t = 0; t < 2; ++t) {
    const int r = wm + t * 16 + ln16;
    offA[t] = r * 64 + ((quad ^ ((r >> 1) & 3)) * 16);
  }
#pragma unroll
  for (int u = 0; u < 4; ++u) {
    const int rn = u * 16 + ln16;
    offB[u] = rn * 64 + ((quad ^ ((rn >> 1) & 3)) * 16);
  }

  f32x4 acc[2][4] = {};
  const char* smb = (const char*)sm;

  for (int k0 = 0; k0 < K; k0 += 32) {
    if (wave < 2) {
#pragma unroll
      for (int inst = 0; inst < 8; ++inst)
        async_cp16(src + goff[inst] + k0,
                   (unsigned short*)((char*)dst0 + inst * 1024));
    } else if (wave == 2) {
#pragma unroll
      for (int inst = 0; inst < 4; ++inst)
        async_cp16(src + goff[inst] + k0,
                   (unsigned short*)((char*)dst0 + inst * 1024));
    }
    __syncthreads();

    short8 ah[2], al[2], bh[4];
#pragma unroll
    for (int t = 0; t < 2; ++t) {
      ah[t] = *(const short8*)(smb + offA[t]);
      al[t] = *(const short8*)(smb + 8192 + offA[t]);
    }
#pragma unroll
    for (int u = 0; u < 4; ++u) bh[u] = *(const short8*)(smb + 16384 + offB[u]);
#pragma unroll
    for (int t = 0; t < 2; ++t)
#pragma unroll
      for (int u = 0; u < 4; ++u) {
        acc[t][u] = __builtin_amdgcn_mfma_f32_16x16x32_bf16(ah[t], bh[u], acc[t][u], 0, 0, 0);
        acc[t][u] = __builtin_amdgcn_mfma_f32_16x16x32_bf16(al[t], bh[u], acc[t][u], 0, 0, 0);
      }
    __syncthreads();
  }

#pragma unroll
  for (int u = 0; u < 4; ++u) {
    const int col = n0 + u * 16 + ln16;
    const float bv = bias[col];
#pragma unroll
    for (int t = 0; t < 2; ++t) {
      const int row0 = m0 + wm + t * 16 + quad * 4;
#pragma unroll
      for (int e = 0; e < 4; ++e)
        C[(size_t)(row0 + e) * N + col] = acc[t][u][e] + bv;
    }
  }
}

// ---------------------------------------------------------------------------
// MFMA sliding-window attention, register softmax. Block = (b,h,32 queries).
// Phase 1: S = Qh @ Kh^T (pure bf16 — score-path error budget allows it),
//          unrolled; exp in-reg (no rowmax, scores bounded ~1.3),
//          unnormalized P -> bf16 LDS, row sums via shfl_xor + one LDS
//          exchange. ONE barrier.
// Phase 2: O = P @ Vh (V-hi only: dropped Vl term contributes ~1.2e-4 to the
//          final output — below the w_out-rounding noise floor).
// Epilogue: scale by 1/rowsum, LDS bounce, coalesced split-bf16 stores.
// ---------------------------------------------------------------------------
__global__ __launch_bounds__(256, 4) void attn_mfma(
    const unsigned short* __restrict__ qk_h,
    const unsigned short* __restrict__ vT_h,
    unsigned short* __restrict__ attn_h,
    unsigned short* __restrict__ attn_l) {
  __shared__ unsigned short P[TQ * PST];  // 18944 B (epilogue reuses as fp32)
  __shared__ float redS[2][32];

  const int b   = blockIdx.z;
  const int h   = blockIdx.y;
  const int i0  = blockIdx.x * TQ;
  const int tid = threadIdx.x;
  const int wave = tid >> 6, lane = tid & 63;
  const int quad = lane >> 4, ln16 = lane & 15;
  const int mt = wave >> 1, np = wave & 1;
  const int jlo = i0 - HALF_;
  const int rbase = mt * 16 + quad * 4;

  // ---- phase 1: scores -> exp -> P(bf16, unnormalized) + row sums --------
  float s[4] = {0.f, 0.f, 0.f, 0.f};
  {
    const size_t qbase =
        ((size_t)(b * L_ + i0 + mt * 16 + ln16) * 2 + 0) * 1024 + h * 64 + quad * 8;
    const short8 qh0 = *(const short8*)&qk_h[qbase];
    const short8 qh1 = *(const short8*)&qk_h[qbase + 32];

#pragma unroll
    for (int c = 0; c < 9; ++c) {
      const int nt   = np + 2 * c;
      const int jabs = jlo + nt * 16 + ln16;
      const int jcl  = min(max(jabs, 0), L_ - 1);
      const size_t kbase =
          ((size_t)(b * L_ + jcl) * 2 + 1) * 1024 + h * 64 + quad * 8;
      const short8 kh0 = *(const short8*)&qk_h[kbase];
      const short8 kh1 = *(const short8*)&qk_h[kbase + 32];

      f32x4 a = {};
      a = __builtin_amdgcn_mfma_f32_16x16x32_bf16(qh0, kh0, a, 0, 0, 0);
      a = __builtin_amdgcn_mfma_f32_16x16x32_bf16(qh1, kh1, a, 0, 0, 0);

      const int colj = nt * 16 + ln16;
#pragma unroll
      for (int e = 0; e < 4; ++e) {
        const int iabs = i0 + rbase + e;
        const bool ok = (jabs >= 0) && (jabs < L_) && (abs(iabs - jabs) <= HALF_);
        const float ev = ok ? __expf(a[e] * 0.125f) : 0.f;
        s[e] += ev;
        P[(rbase + e) * PST + colj] = f2bf(ev);
      }
    }
  }
  // row-sum reduce across the 16 ln16 lanes (stays within quad)
#pragma unroll
  for (int e = 0; e < 4; ++e) {
    s[e] += __shfl_xor(s[e], 1);
    s[e] += __shfl_xor(s[e], 2);
    s[e] += __shfl_xor(s[e], 4);
    s[e] += __shfl_xor(s[e], 8);
  }
  if (ln16 == 0) {
#pragma unroll
    for (int e = 0; e < 4; ++e) redS[np][rbase + e] = s[e];
  }
  __syncthreads();  // covers P writes AND redS exchange
  float rinv[4];
#pragma unroll
  for (int e = 0; e < 4; ++e) rinv[e] = 1.f / (s[e] + redS[np ^ 1][rbase + e]);

  // ---- phase 2: O = P @ Vh -----------------------------------------------
  f32x4 o[2] = {};
  {
    const int dp = np;
    const char* pb = (const char*)P;
#pragma unroll
    for (int c = 0; c < 9; ++c) {
      const short8 pf =
          *(const short8*)(pb + (mt * 16 + ln16) * (PST * 2) + c * 64 + quad * 16);
      int j0 = jlo + c * 32 + quad * 8;
      j0 = min(max(j0, 0), L_ - 8);
#pragma unroll
      for (int t = 0; t < 2; ++t) {
        const size_t vb =
            ((size_t)b * 1024 + h * 64 + dp * 32 + t * 16 + ln16) * 2048 + j0;
        const short8 vh = *(const short8*)&vT_h[vb];
        o[t] = __builtin_amdgcn_mfma_f32_16x16x32_bf16(pf, vh, o[t], 0, 0, 0);
      }
    }
  }

  // ---- epilogue: normalize, LDS bounce, coalesced split-bf16 stores ------
  __syncthreads();  // P slab dead
  float* ob = (float*)P;  // 32 rows x 68-float stride = 8704 B
  {
    const int dp = np;
#pragma unroll
    for (int t = 0; t < 2; ++t)
#pragma unroll
      for (int e = 0; e < 4; ++e)
        ob[(rbase + e) * 68 + dp * 32 + t * 16 + ln16] = o[t][e] * rinv[e];
  }
  __syncthreads();
  {
    const int rr = tid >> 3, ck = tid & 7;
    const float* rp = ob + rr * 68 + ck * 8;
    const float4 f0 = *(const float4*)&rp[0];
    const float4 f1 = *(const float4*)&rp[4];
    float fv[8] = {f0.x, f0.y, f0.z, f0.w, f1.x, f1.y, f1.z, f1.w};
    short8 hh, ll;
#pragma unroll
    for (int i = 0; i < 8; ++i) {
      unsigned short h2, l2;
      split1(fv[i], h2, l2);
      hh[i] = (short)h2; ll[i] = (short)l2;
    }
    const size_t oo = ((size_t)(b * L_ + i0 + rr)) * 1024 + h * 64 + ck * 8;
    *(short8*)&attn_h[oo] = hh;
    *(short8*)&attn_l[oo] = ll;
  }
}

// ---------------------------------------------------------------------------
extern "C" void kernel_launch(void* const* d_in, const int* in_sizes, int n_in,
                              void* d_out, int out_size, void* d_ws, size_t ws_size,
                              hipStream_t stream) {
  const float* x     = (const float*)d_in[0];
  const float* w_qkv = (const float*)d_in[1];
  const float* b_qkv = (const float*)d_in[2];
  const float* w_out = (const float*)d_in[3];
  const float* b_out = (const float*)d_in[4];
  float* out = (float*)d_out;

  const int M = B_ * L_;  // 4096

  // workspace layout (bytes), total 76 MiB:
  //   x_hi @0 (8MiB)     x_lo @8MiB (8MiB)     [dead after QKV gemm]
  //   wqkvT @16MiB (6MiB)
  //   woutT @22MiB (2MiB)
  //   qk_hi @28MiB (16MiB)  qk_lo @44MiB (16MiB)   [B,L,2,1024]
  //   vT_h @60MiB (8MiB)    vT_l @68MiB (8MiB)     [B,1024,L]
  // aliases over dead x region: attn_hi @0, attn_lo @8MiB
  char* ws = (char*)d_ws;
  unsigned short* x_hi    = (unsigned short*)(ws + 0);
  unsigned short* x_lo    = (unsigned short*)(ws + 8388608);
  unsigned short* wqkvT   = (unsigned short*)(ws + 16777216);
  unsigned short* woutT   = (unsigned short*)(ws + 23068672);
  unsigned short* qk_hi   = (unsigned short*)(ws + 29360128);
  unsigned short* qk_lo   = (unsigned short*)(ws + 46137344);
  unsigned short* vT_h    = (unsigned short*)(ws + 62914560);
  unsigned short* vT_l    = (unsigned short*)(ws + 71303168);
  unsigned short* attn_hi = (unsigned short*)(ws + 0);
  unsigned short* attn_lo = (unsigned short*)(ws + 8388608);

  // 1) fused prep: x split + both weight transposes
  prep<<<8192, 256, 0, stream>>>(x, x_hi, x_lo, w_qkv, wqkvT, w_out, woutT);
  // 2) QKV projection -> qk (split bf16) + vT (split planes)  [r8-exact]
  {
    dim3 g(3 * D_ / 128, M / 128);
    gemm_qkv<<<g, 256, 0, stream>>>(x_hi, x_lo, wqkvT, b_qkv,
                                    qk_hi, qk_lo, vT_h, vT_l, 3 * D_, D_);
  }
  // 3) MFMA banded attention -> attn split bf16 (aliases dead x)
  {
    dim3 g(L_ / TQ, H_, B_);
    attn_mfma<<<g, 256, 0, stream>>>(qk_hi, vT_h, attn_hi, attn_lo);
  }
  // 4) output projection -> fp32 d_out (128x64 tiles, 512 blocks = 2/CU)
  {
    dim3 g(D_ / 64, M / 128);
    gemm_n64<<<g, 256, 0, stream>>>(attn_hi, attn_lo, woutT, b_out, out,
                                    D_, D_);
  }
}

// Round 11
// 197.266 us; speedup vs baseline: 1.3133x; 1.1109x over previous
//
#include <hip/hip_runtime.h>
#include <math.h>

#define B_    2
#define L_    2048
#define D_    1024
#define H_    16
#define HD_   64
#define HALF_ 128
#define TQ    32          // queries per attention block
#define PST   296         // bf16 P-slab row stride (shorts); 16B-aligned, bank-tiled

typedef __attribute__((ext_vector_type(8))) short short8;
typedef __attribute__((ext_vector_type(4))) float f32x4;

// ---- bf16 helpers (bitwise, RNE) -----------------------------------------
__device__ __forceinline__ unsigned short f2bf(float x) {
  unsigned int u = __float_as_uint(x);
  u = (u + 0x7fffu + ((u >> 16) & 1u)) >> 16;
  return (unsigned short)u;
}
__device__ __forceinline__ float bf2f(unsigned short b) {
  return __uint_as_float(((unsigned int)b) << 16);
}
__device__ __forceinline__ void split1(float a, unsigned short& h, unsigned short& l) {
  h = f2bf(a);
  l = f2bf(a - bf2f(h));
}

__device__ __forceinline__ void async_cp16(const unsigned short* g, unsigned short* l) {
  __builtin_amdgcn_global_load_lds(
      (const __attribute__((address_space(1))) unsigned int*)g,
      (__attribute__((address_space(3))) unsigned int*)l, 16, 0, 0);
}

// ---------------------------------------------------------------------------
// prep: fused (a) x -> hi/lo bf16 split, (b) w_qkv transpose+round,
//       (c) w_out transpose+round.  Branch is block-uniform.
// ---------------------------------------------------------------------------
__device__ __forceinline__ void tr_round32(const float* __restrict__ in,
                                           unsigned short* __restrict__ hi,
                                           int N, int K, int n0, int k0,
                                           float (*t)[33], int tid) {
  {
    const int kl = tid >> 3, nl = (tid & 7) * 4;
    const float4 v = *(const float4*)&in[(size_t)(k0 + kl) * N + n0 + nl];
    t[kl][nl + 0] = v.x; t[kl][nl + 1] = v.y;
    t[kl][nl + 2] = v.z; t[kl][nl + 3] = v.w;
  }
  __syncthreads();
  {
    const int no = tid >> 3, ko = (tid & 7) * 4;
    ushort4 h;
    h.x = f2bf(t[ko + 0][no]);
    h.y = f2bf(t[ko + 1][no]);
    h.z = f2bf(t[ko + 2][no]);
    h.w = f2bf(t[ko + 3][no]);
    *(ushort4*)&hi[(size_t)(n0 + no) * K + k0 + ko] = h;
  }
}

__global__ __launch_bounds__(256) void prep(const float* __restrict__ x,
                                            unsigned short* __restrict__ x_hi,
                                            unsigned short* __restrict__ x_lo,
                                            const float* __restrict__ w_qkv,
                                            unsigned short* __restrict__ wqkvT,
                                            const float* __restrict__ w_out,
                                            unsigned short* __restrict__ woutT) {
  __shared__ float t[32][33];
  const int bx = blockIdx.x, tid = threadIdx.x;
  if (bx < 4096) {
    const int i = (bx * 256 + tid) * 4;
    const float4 a = *(const float4*)&x[i];
    ushort4 h, l;
    split1(a.x, h.x, l.x);
    split1(a.y, h.y, l.y);
    split1(a.z, h.z, l.z);
    split1(a.w, h.w, l.w);
    *(ushort4*)&x_hi[i] = h;
    *(ushort4*)&x_lo[i] = l;
  } else if (bx < 7168) {
    const int tb = bx - 4096;  // 96 x 32 tiles
    tr_round32(w_qkv, wqkvT, 3 * D_, D_, (tb % 96) * 32, (tb / 96) * 32, t, tid);
  } else {
    const int tb = bx - 7168;  // 32 x 32 tiles
    tr_round32(w_out, woutT, D_, D_, (tb % 32) * 32, (tb / 32) * 32, t, tid);
  }
}

// ---------------------------------------------------------------------------
// 2-product split-bf16 MFMA GEMM (QKV): C = (Ah+Al) @ Bh^T + bias.
// 128x128 tile, BK=32, 4 waves (3 stage, all compute). r8-exact K-loop —
// NO conditionals in the K-loop (r6/r7/r9 all regressed from them).
// Epilogue (attention-frag-tiled, hi planes only — lo planes were dead):
//   q -> q_hi[B*L, 1024]                       (scalar bf16 stores)
//   k -> kT[b][h][dg(8)][j(2048)][8d]          (scalar bf16 stores, coalesced
//                                               16B/lane reads in attention)
//   v -> vTile[b][jg(256)][d(1024)][8j]        (ushort4 stores, coalesced
//                                               16B/lane reads in attention)
// ---------------------------------------------------------------------------
__global__ __launch_bounds__(256) void gemm_qkv(const unsigned short* __restrict__ Ah,
                                                const unsigned short* __restrict__ Al,
                                                const unsigned short* __restrict__ Bh,
                                                const float* __restrict__ bias,
                                                unsigned short* __restrict__ q_hi,
                                                unsigned short* __restrict__ kT,
                                                unsigned short* __restrict__ vTile,
                                                int N, int K) {
  __shared__ unsigned short sm[3 * 4096];  // 24 KB: Ah | Al | Bh
  const int tid  = threadIdx.x;
  const int wave = tid >> 6, lane = tid & 63;
  const int m0 = blockIdx.y * 128, n0 = blockIdx.x * 128;
  const int wm = (wave >> 1) * 64, wn = (wave & 1) * 64;
  const int quad = lane >> 4, ln16 = lane & 15;

  const unsigned short* src = (wave == 0) ? Ah : (wave == 1) ? Al : Bh;
  const int baserow = (wave < 2) ? m0 : n0;
  size_t goff[8];
#pragma unroll
  for (int inst = 0; inst < 8; ++inst) {
    const int r = inst * 16 + (lane >> 2);
    const int q = (lane & 3) ^ ((r >> 1) & 3);
    goff[inst] = (size_t)(baserow + r) * K + q * 8;
  }
  unsigned short* dst0 = &sm[(wave < 3 ? wave : 2) * 4096];

  int offA[4], offB[4];
#pragma unroll
  for (int t = 0; t < 4; ++t) {
    const int r = wm + t * 16 + ln16;
    offA[t] = r * 64 + ((quad ^ ((r >> 1) & 3)) * 16);
    const int rn = wn + t * 16 + ln16;
    offB[t] = rn * 64 + ((quad ^ ((rn >> 1) & 3)) * 16);
  }

  f32x4 acc[4][4] = {};
  const char* smb = (const char*)sm;

  for (int k0 = 0; k0 < K; k0 += 32) {
    if (wave < 3) {
#pragma unroll
      for (int inst = 0; inst < 8; ++inst)
        async_cp16(src + goff[inst] + k0,
                   (unsigned short*)((char*)dst0 + inst * 1024));
    }
    __syncthreads();

    short8 ah[4], al[4], bh[4];
#pragma unroll
    for (int t = 0; t < 4; ++t) {
      ah[t] = *(const short8*)(smb + offA[t]);
      al[t] = *(const short8*)(smb + 8192 + offA[t]);
      bh[t] = *(const short8*)(smb + 16384 + offB[t]);
    }
#pragma unroll
    for (int t = 0; t < 4; ++t)
#pragma unroll
      for (int u = 0; u < 4; ++u) {
        acc[t][u] = __builtin_amdgcn_mfma_f32_16x16x32_bf16(ah[t], bh[u], acc[t][u], 0, 0, 0);
        acc[t][u] = __builtin_amdgcn_mfma_f32_16x16x32_bf16(al[t], bh[u], acc[t][u], 0, 0, 0);
      }
    __syncthreads();
  }

#pragma unroll
  for (int u = 0; u < 4; ++u) {
    const int col = n0 + wn + u * 16 + ln16;
    const float bv = bias[col];
    const int slot = col >> 10;   // 0=q,1=k,2=v (wave-uniform per u-tile)
    const int hd   = col & 1023;
    const int hh_  = hd >> 6;     // head
    const int dg   = (hd & 63) >> 3, di = hd & 7;
#pragma unroll
    for (int t = 0; t < 4; ++t) {
      const int row0 = m0 + wm + t * 16 + quad * 4;
      if (slot == 0) {
#pragma unroll
        for (int e = 0; e < 4; ++e)
          q_hi[(size_t)(row0 + e) * 1024 + hd] = f2bf(acc[t][u][e] + bv);
      } else if (slot == 1) {
#pragma unroll
        for (int e = 0; e < 4; ++e) {
          const int tok = row0 + e;
          const int bb = tok >> 11, j = tok & 2047;
          const size_t o =
              ((((size_t)bb * 16 + hh_) * 8 + dg) * 2048 + j) * 8 + di;
          kT[o] = f2bf(acc[t][u][e] + bv);
        }
      } else {
        const int bb = row0 >> 11, l0 = row0 & 2047;
        ushort4 vh;
        vh.x = f2bf(acc[t][u][0] + bv);
        vh.y = f2bf(acc[t][u][1] + bv);
        vh.z = f2bf(acc[t][u][2] + bv);
        vh.w = f2bf(acc[t][u][3] + bv);
        const size_t o =
            (((size_t)bb * 256 + (l0 >> 3)) * 1024 + hd) * 8 + (l0 & 7);
        *(ushort4*)&vTile[o] = vh;
      }
    }
  }
}

// ---------------------------------------------------------------------------
// Out-projection GEMM: C = (Ah+Al) @ Bh^T + bias, fp32 out.
// 128x64 tile, BK=32, 512 blocks (2/CU). 20 KB LDS.
// ---------------------------------------------------------------------------
__global__ __launch_bounds__(256) void gemm_n64(const unsigned short* __restrict__ Ah,
                                                const unsigned short* __restrict__ Al,
                                                const unsigned short* __restrict__ Bh,
                                                const float* __restrict__ bias,
                                                float* __restrict__ C,
                                                int N, int K) {
  __shared__ unsigned short sm[2 * 4096 + 2048];  // 20 KB: Ah | Al | Bh
  const int tid  = threadIdx.x;
  const int wave = tid >> 6, lane = tid & 63;
  const int m0 = blockIdx.y * 128, n0 = blockIdx.x * 64;
  const int quad = lane >> 4, ln16 = lane & 15;
  const int wm = wave * 32;

  const unsigned short* src = (wave == 0) ? Ah : (wave == 1) ? Al : Bh;
  const int baserow = (wave < 2) ? m0 : n0;
  size_t goff[8];
#pragma unroll
  for (int inst = 0; inst < 8; ++inst) {
    const int r = inst * 16 + (lane >> 2);
    const int q = (lane & 3) ^ ((r >> 1) & 3);
    goff[inst] = (size_t)(baserow + r) * K + q * 8;
  }
  unsigned short* dst0 = &sm[(wave < 2 ? wave : 2) * 4096];

  int offA[2], offB[4];
#pragma unroll
  for (int t = 0; t < 2; ++t) {
    const int r = wm + t * 16 + ln16;
    offA[t] = r * 64 + ((quad ^ ((r >> 1) & 3)) * 16);
  }
#pragma unroll
  for (int u = 0; u < 4; ++u) {
    const int rn = u * 16 + ln16;
    offB[u] = rn * 64 + ((quad ^ ((rn >> 1) & 3)) * 16);
  }

  f32x4 acc[2][4] = {};
  const char* smb = (const char*)sm;

  for (int k0 = 0; k0 < K; k0 += 32) {
    if (wave < 2) {
#pragma unroll
      for (int inst = 0; inst < 8; ++inst)
        async_cp16(src + goff[inst] + k0,
                   (unsigned short*)((char*)dst0 + inst * 1024));
    } else if (wave == 2) {
#pragma unroll
      for (int inst = 0; inst < 4; ++inst)
        async_cp16(src + goff[inst] + k0,
                   (unsigned short*)((char*)dst0 + inst * 1024));
    }
    __syncthreads();

    short8 ah[2], al[2], bh[4];
#pragma unroll
    for (int t = 0; t < 2; ++t) {
      ah[t] = *(const short8*)(smb + offA[t]);
      al[t] = *(const short8*)(smb + 8192 + offA[t]);
    }
#pragma unroll
    for (int u = 0; u < 4; ++u) bh[u] = *(const short8*)(smb + 16384 + offB[u]);
#pragma unroll
    for (int t = 0; t < 2; ++t)
#pragma unroll
      for (int u = 0; u < 4; ++u) {
        acc[t][u] = __builtin_amdgcn_mfma_f32_16x16x32_bf16(ah[t], bh[u], acc[t][u], 0, 0, 0);
        acc[t][u] = __builtin_amdgcn_mfma_f32_16x16x32_bf16(al[t], bh[u], acc[t][u], 0, 0, 0);
      }
    __syncthreads();
  }

#pragma unroll
  for (int u = 0; u < 4; ++u) {
    const int col = n0 + u * 16 + ln16;
    const float bv = bias[col];
#pragma unroll
    for (int t = 0; t < 2; ++t) {
      const int row0 = m0 + wm + t * 16 + quad * 4;
#pragma unroll
      for (int e = 0; e < 4; ++e)
        C[(size_t)(row0 + e) * N + col] = acc[t][u][e] + bv;
    }
  }
}

// ---------------------------------------------------------------------------
// MFMA sliding-window attention, register softmax. Block = (b,h,32 queries).
// Phase 1: S = Qh @ Kh^T; K loaded from frag-tiled kT -> every lane's 16B is
//          adjacent to its neighbor's (coalesced; was 4KB-strided).
// Phase 2: O = P @ Vh; V loaded from frag-tiled vTile (coalesced).
// Epilogue: scale by 1/rowsum, LDS bounce, coalesced split-bf16 stores.
// ---------------------------------------------------------------------------
__global__ __launch_bounds__(256, 4) void attn_mfma(
    const unsigned short* __restrict__ q_hi,
    const unsigned short* __restrict__ kT,
    const unsigned short* __restrict__ vTile,
    unsigned short* __restrict__ attn_h,
    unsigned short* __restrict__ attn_l) {
  __shared__ unsigned short P[TQ * PST];  // 18944 B (epilogue reuses as fp32)
  __shared__ float redS[2][32];

  const int b   = blockIdx.z;
  const int h   = blockIdx.y;
  const int i0  = blockIdx.x * TQ;
  const int tid = threadIdx.x;
  const int wave = tid >> 6, lane = tid & 63;
  const int quad = lane >> 4, ln16 = lane & 15;
  const int mt = wave >> 1, np = wave & 1;
  const int jlo = i0 - HALF_;
  const int rbase = mt * 16 + quad * 4;

  // ---- phase 1: scores -> exp -> P(bf16, unnormalized) + row sums --------
  float s[4] = {0.f, 0.f, 0.f, 0.f};
  {
    const size_t qbase =
        (size_t)(b * L_ + i0 + mt * 16 + ln16) * 1024 + h * 64 + quad * 8;
    const short8 qh0 = *(const short8*)&q_hi[qbase];
    const short8 qh1 = *(const short8*)&q_hi[qbase + 32];

    // kT row bases for this (b,h,quad): dg=quad and dg=quad+4... wait, the
    // second fragment covers d=32+quad*8 -> dg = 4+quad.
    const size_t kb0 = (((size_t)b * 16 + h) * 8 + quad) * 2048 * 8;
    const size_t kb1 = (((size_t)b * 16 + h) * 8 + quad + 4) * 2048 * 8;

#pragma unroll
    for (int c = 0; c < 9; ++c) {
      const int nt   = np + 2 * c;
      const int jabs = jlo + nt * 16 + ln16;
      const int jcl  = min(max(jabs, 0), L_ - 1);
      const short8 kh0 = *(const short8*)&kT[kb0 + (size_t)jcl * 8];
      const short8 kh1 = *(const short8*)&kT[kb1 + (size_t)jcl * 8];

      f32x4 a = {};
      a = __builtin_amdgcn_mfma_f32_16x16x32_bf16(qh0, kh0, a, 0, 0, 0);
      a = __builtin_amdgcn_mfma_f32_16x16x32_bf16(qh1, kh1, a, 0, 0, 0);

      const int colj = nt * 16 + ln16;
#pragma unroll
      for (int e = 0; e < 4; ++e) {
        const int iabs = i0 + rbase + e;
        const bool ok = (jabs >= 0) && (jabs < L_) && (abs(iabs - jabs) <= HALF_);
        const float ev = ok ? __expf(a[e] * 0.125f) : 0.f;
        s[e] += ev;
        P[(rbase + e) * PST + colj] = f2bf(ev);
      }
    }
  }
  // row-sum reduce across the 16 ln16 lanes (stays within quad)
#pragma unroll
  for (int e = 0; e < 4; ++e) {
    s[e] += __shfl_xor(s[e], 1);
    s[e] += __shfl_xor(s[e], 2);
    s[e] += __shfl_xor(s[e], 4);
    s[e] += __shfl_xor(s[e], 8);
  }
  if (ln16 == 0) {
#pragma unroll
    for (int e = 0; e < 4; ++e) redS[np][rbase + e] = s[e];
  }
  __syncthreads();  // covers P writes AND redS exchange
  float rinv[4];
#pragma unroll
  for (int e = 0; e < 4; ++e) rinv[e] = 1.f / (s[e] + redS[np ^ 1][rbase + e]);

  // ---- phase 2: O = P @ Vh (frag-tiled vTile, coalesced) ------------------
  f32x4 o[2] = {};
  {
    const int dp = np;
    const char* pb = (const char*)P;
#pragma unroll
    for (int c = 0; c < 9; ++c) {
      const short8 pf =
          *(const short8*)(pb + (mt * 16 + ln16) * (PST * 2) + c * 64 + quad * 16);
      int j0 = jlo + c * 32 + quad * 8;
      j0 = min(max(j0, 0), L_ - 8);  // stays a multiple of 8
      const size_t jgbase = ((size_t)b * 256 + (j0 >> 3)) * 1024;
#pragma unroll
      for (int t = 0; t < 2; ++t) {
        const size_t vb =
            (jgbase + (h * 64 + dp * 32 + t * 16 + ln16)) * 8;
        const short8 vh = *(const short8*)&vTile[vb];
        o[t] = __builtin_amdgcn_mfma_f32_16x16x32_bf16(pf, vh, o[t], 0, 0, 0);
      }
    }
  }

  // ---- epilogue: normalize, LDS bounce, coalesced split-bf16 stores ------
  __syncthreads();  // P slab dead
  float* ob = (float*)P;  // 32 rows x 68-float stride = 8704 B
  {
    const int dp = np;
#pragma unroll
    for (int t = 0; t < 2; ++t)
#pragma unroll
      for (int e = 0; e < 4; ++e)
        ob[(rbase + e) * 68 + dp * 32 + t * 16 + ln16] = o[t][e] * rinv[e];
  }
  __syncthreads();
  {
    const int rr = tid >> 3, ck = tid & 7;
    const float* rp = ob + rr * 68 + ck * 8;
    const float4 f0 = *(const float4*)&rp[0];
    const float4 f1 = *(const float4*)&rp[4];
    float fv[8] = {f0.x, f0.y, f0.z, f0.w, f1.x, f1.y, f1.z, f1.w};
    short8 hh, ll;
#pragma unroll
    for (int i = 0; i < 8; ++i) {
      unsigned short h2, l2;
      split1(fv[i], h2, l2);
      hh[i] = (short)h2; ll[i] = (short)l2;
    }
    const size_t oo = ((size_t)(b * L_ + i0 + rr)) * 1024 + h * 64 + ck * 8;
    *(short8*)&attn_h[oo] = hh;
    *(short8*)&attn_l[oo] = ll;
  }
}

// ---------------------------------------------------------------------------
extern "C" void kernel_launch(void* const* d_in, const int* in_sizes, int n_in,
                              void* d_out, int out_size, void* d_ws, size_t ws_size,
                              hipStream_t stream) {
  const float* x     = (const float*)d_in[0];
  const float* w_qkv = (const float*)d_in[1];
  const float* b_qkv = (const float*)d_in[2];
  const float* w_out = (const float*)d_in[3];
  const float* b_out = (const float*)d_in[4];
  float* out = (float*)d_out;

  const int M = B_ * L_;  // 4096

  // workspace layout (bytes), total 48 MiB:
  //   x_hi @0 (8MiB)     x_lo @8MiB (8MiB)     [dead after QKV gemm]
  //   wqkvT @16MiB (6MiB)
  //   woutT @22MiB (2MiB)
  //   q_hi  @24MiB (8MiB)   [B*L, 1024]
  //   kT    @32MiB (8MiB)   [b][h][dg8][j2048][8d]
  //   vTile @40MiB (8MiB)   [b][jg256][d1024][8j]
  // aliases over dead x region: attn_hi @0, attn_lo @8MiB
  char* ws = (char*)d_ws;
  unsigned short* x_hi    = (unsigned short*)(ws + 0);
  unsigned short* x_lo    = (unsigned short*)(ws + 8388608);
  unsigned short* wqkvT   = (unsigned short*)(ws + 16777216);
  unsigned short* woutT   = (unsigned short*)(ws + 23068672);
  unsigned short* q_hi    = (unsigned short*)(ws + 25165824);
  unsigned short* kT      = (unsigned short*)(ws + 33554432);
  unsigned short* vTile   = (unsigned short*)(ws + 41943040);
  unsigned short* attn_hi = (unsigned short*)(ws + 0);
  unsigned short* attn_lo = (unsigned short*)(ws + 8388608);

  // 1) fused prep: x split + both weight transposes
  prep<<<8192, 256, 0, stream>>>(x, x_hi, x_lo, w_qkv, wqkvT, w_out, woutT);
  // 2) QKV projection -> q_hi + kT + vTile (attention-frag-tiled, hi only)
  {
    dim3 g(3 * D_ / 128, M / 128);
    gemm_qkv<<<g, 256, 0, stream>>>(x_hi, x_lo, wqkvT, b_qkv,
                                    q_hi, kT, vTile, 3 * D_, D_);
  }
  // 3) MFMA banded attention -> attn split bf16 (aliases dead x)
  {
    dim3 g(L_ / TQ, H_, B_);
    attn_mfma<<<g, 256, 0, stream>>>(q_hi, kT, vTile, attn_hi, attn_lo);
  }
  // 4) output projection -> fp32 d_out (128x64 tiles, 512 blocks = 2/CU)
  {
    dim3 g(D_ / 64, M / 128);
    gemm_n64<<<g, 256, 0, stream>>>(attn_hi, attn_lo, woutT, b_out, out,
                                    D_, D_);
  }
}